// Round 16
// baseline (258.144 us; speedup 1.0000x reference)
//
#include <hip/hip_runtime.h>
#include <hip/hip_bf16.h>
#include <stdint.h>

#define BTOT 4096
#define RR   64
#define DIMD 128

typedef short s16x8 __attribute__((ext_vector_type(8)));
typedef float f32x4 __attribute__((ext_vector_type(4)));

__device__ __forceinline__ unsigned short f2bf(float x) {
  __hip_bfloat16 h = __float2bfloat16(x);
  return __builtin_bit_cast(unsigned short, h);
}
__device__ __forceinline__ unsigned int pk2(float lo, float hi) {
  return ((unsigned int)f2bf(hi) << 16) | (unsigned int)f2bf(lo);
}
__device__ __forceinline__ float bflo(unsigned int u) {
  return __builtin_bit_cast(float, u << 16);
}
__device__ __forceinline__ float bfhi(unsigned int u) {
  return __builtin_bit_cast(float, u & 0xFFFF0000u);
}

// ---------------------------------------------------------------------------
// Pre-kernel: qproj[b,k] = sum_d query_r[b,d]*W1[k,128+d] + b1[k]  (fp32),
// offset_emb passthrough, and blocks 0/1 emit PERMUTED+swizzled bf16 copies
// of W1a / W2 into ws. d-permutation pi(s) = 32*(s>>5) + 16*((s>>2)&1) +
// 4*((s>>3)&3) + (s&3) makes the main kernel's B-fragments (rr, h) equal
// plain in-lane register packs (no LDS transpose round trips). On top,
// bank-XOR: stored addr = k*128 + (s ^ ((k&7)<<3)).
// ---------------------------------------------------------------------------
__global__ __launch_bounds__(256) void prep_kernel(
    const float* __restrict__ W1, const float* __restrict__ b1,
    const float* __restrict__ query_r, const float* __restrict__ W2,
    const float* __restrict__ offset_emb,
    float* __restrict__ qproj, unsigned short* __restrict__ w1a_t,
    unsigned short* __restrict__ w2_t, float* __restrict__ out)
{
  __shared__ float w1b[128 * 132];   // +4 pad
  __shared__ float qrs[256];
  const int tid = threadIdx.x;

  { // offset_emb passthrough (1 float4 per thread; 512 blocks cover 4096x128)
    const size_t ob = (size_t)blockIdx.x * 8 * DIMD + (size_t)tid * 4;
    *reinterpret_cast<float4*>(out + (size_t)BTOT * DIMD + ob) =
        *reinterpret_cast<const float4*>(offset_emb + ob);
  }
  { // stage W1b fp32 into padded LDS
    const int k = tid >> 1, d0 = (tid & 1) * 64;
    const float* src = W1 + k * 256 + 128 + d0;
    float* dst = &w1b[k * 132 + d0];
    #pragma unroll
    for (int i = 0; i < 64; i += 4)
      *reinterpret_cast<float4*>(dst + i) = *reinterpret_cast<const float4*>(src + i);
  }
  if (blockIdx.x < 2) { // permuted + swizzled bf16 weight tables
    const float* Wsrc = (blockIdx.x == 0) ? W1 : W2;
    unsigned short* dstw = (blockIdx.x == 0) ? w1a_t : w2_t;
    const int stride = (blockIdx.x == 0) ? 256 : 128;
    for (int i = tid; i < 128 * 128; i += 256) {
      const int k = i >> 7, s = i & 127;
      const int d = 32 * (s >> 5) + 16 * ((s >> 2) & 1) + 4 * ((s >> 3) & 3) + (s & 3);
      dstw[k * 128 + (s ^ ((k & 7) << 3))] = f2bf(Wsrc[k * stride + d]);
    }
  }
  __syncthreads();

  const int b0 = blockIdx.x * 8;
  const int k = tid & 127, bh = tid >> 7;
  for (int p = 0; p < 4; ++p) {
    const int b = b0 + p * 2;
    qrs[tid] = query_r[(size_t)(b + bh) * DIMD + k];
    __syncthreads();
    float acc = b1[k];
    const float* qq = &qrs[bh * 128];
    const float* wr = &w1b[k * 132];
    #pragma unroll
    for (int d = 0; d < 128; d += 4) {
      float4 wv = *reinterpret_cast<const float4*>(wr + d);
      float4 qv = *reinterpret_cast<const float4*>(qq + d);
      acc = fmaf(wv.x, qv.x, acc); acc = fmaf(wv.y, qv.y, acc);
      acc = fmaf(wv.z, qv.z, acc); acc = fmaf(wv.w, qv.w, acc);
    }
    qproj[(size_t)(b + bh) * DIMD + k] = acc;
    __syncthreads();
  }
}

// ---------------------------------------------------------------------------
// Main kernel: 512 blocks x 512 threads (8 waves), each wave owns ONE b.
// ZERO LDS round trips in the loop (R15 diagnosis: the 12 serialized
// write->wait->read LDS chains + 64 scalar u16 DS ops/iter were the floor).
// Operand-swapped MFMAs: weights are the A operand (m-dim), rr/h the B
// operand (n-dim = r). With the pi-permuted weight tables:
//  - GEMM1 B-frag = in-lane packed rr loaded straight from global in
//    C-layout float4s [r=c, d=16nt+4g..+3];
//  - GEMM1 output [k=16nt+4g+reg, r=c] -> relu -> pack = GEMM2 B-frag,
//    pure in-lane;
//  - bias (ev-sv-rr) is needed at [r=c, d=16nt+4g+reg] = the load layout;
//    dot = 32 in-lane FMAs; r-sum accumulates in-lane across iterations,
//    one 4-step butterfly over the 16 c-lanes per b at the end.
// Main loop: 24 independent float4 global loads + 64 pipelined b128 weight
// reads + 64 MFMA per iteration. No barriers, no fences, no LDS writes.
// LDS = 64 KB (weights only). Bare __launch_bounds__(512) (never-spilled
// codegen family).
// ---------------------------------------------------------------------------
__global__ __launch_bounds__(512) void main_kernel(
    const float* __restrict__ query_emb,
    const float* __restrict__ refer_embs, const float* __restrict__ refer_r,
    const float* __restrict__ start_embs, const float* __restrict__ b2,
    const float* __restrict__ qproj, const unsigned short* __restrict__ w1a_t,
    const unsigned short* __restrict__ w2_t, float* __restrict__ out)
{
  __shared__ unsigned short lds_w1a[128 * 128];   // 32 KB, permuted+swizzled
  __shared__ unsigned short lds_w2[128 * 128];    // 32 KB, permuted+swizzled

  const int tid  = threadIdx.x;
  const int wave = tid >> 6;
  const int lane = tid & 63;
  const int g    = lane >> 4;   // 0..3
  const int c    = lane & 15;   // r-lane / weight-row-lane

  { // stage weight tables (linear uint4 copy; layout pre-applied in ws)
    const uint4* s1 = reinterpret_cast<const uint4*>(w1a_t);
    const uint4* s2 = reinterpret_cast<const uint4*>(w2_t);
    uint4* d1 = reinterpret_cast<uint4*>(lds_w1a);
    uint4* d2 = reinterpret_cast<uint4*>(lds_w2);
    #pragma unroll
    for (int i = 0; i < 4; ++i) {
      d1[tid + 512 * i] = s1[tid + 512 * i];
      d2[tid + 512 * i] = s2[tid + 512 * i];
    }
  }
  __syncthreads();   // the ONLY barrier

  const int swc = (c & 7) << 3;
  const int b = blockIdx.x * 8 + wave;  // this wave's b

  f32x4 acc[8];
  #pragma unroll
  for (int nt = 0; nt < 8; ++nt) acc[nt] = (f32x4){0.f, 0.f, 0.f, 0.f};

  union U16x8 { unsigned int u[4]; s16x8 v; };

  for (int it = 0; it < 4; ++it) {
    const size_t rowoff = ((size_t)b * RR + it * 16 + c) * DIMD + 4 * g;
    const float* rp = refer_r    + rowoff;
    const float* ep = refer_embs + rowoff;
    const float* sp = start_embs + rowoff;

    unsigned int rrpk[16], bp[16];
    #pragma unroll
    for (int nt = 0; nt < 8; ++nt) {
      const float4 rv = *reinterpret_cast<const float4*>(rp + 16 * nt);
      const float4 ev = *reinterpret_cast<const float4*>(ep + 16 * nt);
      const float4 sv = *reinterpret_cast<const float4*>(sp + 16 * nt);
      rrpk[2 * nt + 0] = pk2(rv.x, rv.y);
      rrpk[2 * nt + 1] = pk2(rv.z, rv.w);
      bp[2 * nt + 0] = pk2(ev.x - sv.x - rv.x, ev.y - sv.y - rv.y);
      bp[2 * nt + 1] = pk2(ev.z - sv.z - rv.z, ev.w - sv.w - rv.w);
    }

    // ---- GEMM1: Ch[k=16nt+4g+reg, r=c] = W1a x rr + qproj
    f32x4 Ch[8];
    #pragma unroll
    for (int nt = 0; nt < 8; ++nt)
      Ch[nt] = *reinterpret_cast<const f32x4*>(qproj + (size_t)b * DIMD + 16 * nt + 4 * g);
    #pragma unroll
    for (int ck = 0; ck < 4; ++ck) {
      U16x8 af;
      af.u[0] = rrpk[4 * ck + 0]; af.u[1] = rrpk[4 * ck + 1];
      af.u[2] = rrpk[4 * ck + 2]; af.u[3] = rrpk[4 * ck + 3];
      #pragma unroll
      for (int nt = 0; nt < 8; ++nt) {
        s16x8 wf = *reinterpret_cast<const s16x8*>(
            &lds_w1a[(nt * 16 + c) * DIMD + ((ck * 32 + g * 8) ^ swc)]);
        Ch[nt] = __builtin_amdgcn_mfma_f32_16x16x32_bf16(wf, af.v, Ch[nt], 0, 0, 0);
      }
    }

    // ---- relu + pack h (in-lane; layout already matches GEMM2 B-frag)
    unsigned int hpk[16];
    #pragma unroll
    for (int nt = 0; nt < 8; ++nt) {
      hpk[2 * nt + 0] = pk2(fmaxf(Ch[nt][0], 0.f), fmaxf(Ch[nt][1], 0.f));
      hpk[2 * nt + 1] = pk2(fmaxf(Ch[nt][2], 0.f), fmaxf(Ch[nt][3], 0.f));
    }

    // ---- GEMM2: Ca[d=16nt+4g+reg, r=c] = W2 x h + b2
    f32x4 Ca[8];
    #pragma unroll
    for (int nt = 0; nt < 8; ++nt)
      Ca[nt] = *reinterpret_cast<const f32x4*>(b2 + 16 * nt + 4 * g);
    #pragma unroll
    for (int ck = 0; ck < 4; ++ck) {
      U16x8 hf;
      hf.u[0] = hpk[4 * ck + 0]; hf.u[1] = hpk[4 * ck + 1];
      hf.u[2] = hpk[4 * ck + 2]; hf.u[3] = hpk[4 * ck + 3];
      #pragma unroll
      for (int nt = 0; nt < 8; ++nt) {
        s16x8 wf = *reinterpret_cast<const s16x8*>(
            &lds_w2[(nt * 16 + c) * DIMD + ((ck * 32 + g * 8) ^ swc)]);
        Ca[nt] = __builtin_amdgcn_mfma_f32_16x16x32_bf16(wf, hf.v, Ca[nt], 0, 0, 0);
      }
    }

    // ---- bias dot (fully in-lane; bias layout == C layout)
    #pragma unroll
    for (int nt = 0; nt < 8; ++nt) {
      acc[nt][0] = fmaf(Ca[nt][0], bflo(bp[2 * nt + 0]), acc[nt][0]);
      acc[nt][1] = fmaf(Ca[nt][1], bfhi(bp[2 * nt + 0]), acc[nt][1]);
      acc[nt][2] = fmaf(Ca[nt][2], bflo(bp[2 * nt + 1]), acc[nt][2]);
      acc[nt][3] = fmaf(Ca[nt][3], bfhi(bp[2 * nt + 1]), acc[nt][3]);
    }
  }

  // ---- r-sum butterfly over the 16 c-lanes (once per b)
  #pragma unroll
  for (int mask = 1; mask <= 8; mask <<= 1)
    #pragma unroll
    for (int nt = 0; nt < 8; ++nt) {
      acc[nt][0] += __shfl_xor(acc[nt][0], mask);
      acc[nt][1] += __shfl_xor(acc[nt][1], mask);
      acc[nt][2] += __shfl_xor(acc[nt][2], mask);
      acc[nt][3] += __shfl_xor(acc[nt][3], mask);
    }

  // ---- epilogue: lanes c==0 (4 lanes, g=0..3) write d=16nt+4g..+3
  if (c == 0) {
    #pragma unroll
    for (int nt = 0; nt < 8; ++nt) {
      const size_t o = (size_t)b * DIMD + 16 * nt + 4 * g;
      const float4 qe = *reinterpret_cast<const float4*>(query_emb + o);
      float4 r;
      r.x = qe.x + acc[nt][0]; r.y = qe.y + acc[nt][1];
      r.z = qe.z + acc[nt][2]; r.w = qe.w + acc[nt][3];
      *reinterpret_cast<float4*>(out + o) = r;
    }
  }
}

extern "C" void kernel_launch(void* const* d_in, const int* in_sizes, int n_in,
                              void* d_out, int out_size, void* d_ws, size_t ws_size,
                              hipStream_t stream) {
  const float* query_emb  = (const float*)d_in[0];
  const float* offset_emb = (const float*)d_in[1];
  const float* refer_embs = (const float*)d_in[2];
  const float* query_r    = (const float*)d_in[3];
  const float* refer_r    = (const float*)d_in[4];
  const float* start_embs = (const float*)d_in[5];
  const float* W1 = (const float*)d_in[6];
  const float* b1 = (const float*)d_in[7];
  const float* W2 = (const float*)d_in[8];
  const float* b2 = (const float*)d_in[9];
  float* out = (float*)d_out;

  float* qproj = (float*)d_ws;                       // 4096*128 f32 = 2 MB
  unsigned short* w1a_t =
      (unsigned short*)((char*)d_ws + (size_t)BTOT * DIMD * sizeof(float));
  unsigned short* w2_t = w1a_t + 128 * 128;          // +32 KB each

  hipLaunchKernelGGL(prep_kernel, dim3(512), dim3(256), 0, stream,
                     W1, b1, query_r, W2, offset_emb, qproj, w1a_t, w2_t, out);
  hipLaunchKernelGGL(main_kernel, dim3(512), dim3(512), 0, stream,
                     query_emb, refer_embs, refer_r, start_embs,
                     b2, qproj, w1a_t, w2_t, out);
}

// Round 17
// 108.994 us; speedup vs baseline: 2.3684x; 2.3684x over previous
//
#include <hip/hip_runtime.h>
#include <hip/hip_bf16.h>
#include <stdint.h>

#define BTOT 4096
#define RR   64
#define DIMD 128

typedef short s16x8 __attribute__((ext_vector_type(8)));
typedef float f32x4 __attribute__((ext_vector_type(4)));

__device__ __forceinline__ unsigned short f2bf(float x) {
  __hip_bfloat16 h = __float2bfloat16(x);
  return __builtin_bit_cast(unsigned short, h);
}
__device__ __forceinline__ unsigned int pk2(float lo, float hi) {
  return ((unsigned int)f2bf(hi) << 16) | (unsigned int)f2bf(lo);
}
__device__ __forceinline__ float bflo(unsigned int u) {
  return __builtin_bit_cast(float, u << 16);
}
__device__ __forceinline__ float bfhi(unsigned int u) {
  return __builtin_bit_cast(float, u & 0xFFFF0000u);
}

// ---------------------------------------------------------------------------
// Pre-kernel: qproj[b,k] = sum_d query_r[b,d]*W1[k,128+d] + b1[k]  (fp32),
// offset_emb passthrough, and blocks 0/1 emit PERMUTED+swizzled bf16 copies
// of W1a / W2 into ws. d-permutation pi(s) = 32*(s>>5) + 16*((s>>2)&1) +
// 4*((s>>3)&3) + (s&3) makes the main kernel's B-fragments (rr, h) equal
// plain in-lane register packs (no LDS transpose round trips). On top,
// bank-XOR: stored addr = k*128 + (s ^ ((k&7)<<3)).  [layout verified: R16
// passed absmax 0.5]
// ---------------------------------------------------------------------------
__global__ __launch_bounds__(256) void prep_kernel(
    const float* __restrict__ W1, const float* __restrict__ b1,
    const float* __restrict__ query_r, const float* __restrict__ W2,
    const float* __restrict__ offset_emb,
    float* __restrict__ qproj, unsigned short* __restrict__ w1a_t,
    unsigned short* __restrict__ w2_t, float* __restrict__ out)
{
  __shared__ float w1b[128 * 132];   // +4 pad
  __shared__ float qrs[256];
  const int tid = threadIdx.x;

  { // offset_emb passthrough (1 float4 per thread; 512 blocks cover 4096x128)
    const size_t ob = (size_t)blockIdx.x * 8 * DIMD + (size_t)tid * 4;
    *reinterpret_cast<float4*>(out + (size_t)BTOT * DIMD + ob) =
        *reinterpret_cast<const float4*>(offset_emb + ob);
  }
  { // stage W1b fp32 into padded LDS
    const int k = tid >> 1, d0 = (tid & 1) * 64;
    const float* src = W1 + k * 256 + 128 + d0;
    float* dst = &w1b[k * 132 + d0];
    #pragma unroll
    for (int i = 0; i < 64; i += 4)
      *reinterpret_cast<float4*>(dst + i) = *reinterpret_cast<const float4*>(src + i);
  }
  if (blockIdx.x < 2) { // permuted + swizzled bf16 weight tables
    const float* Wsrc = (blockIdx.x == 0) ? W1 : W2;
    unsigned short* dstw = (blockIdx.x == 0) ? w1a_t : w2_t;
    const int stride = (blockIdx.x == 0) ? 256 : 128;
    for (int i = tid; i < 128 * 128; i += 256) {
      const int k = i >> 7, s = i & 127;
      const int d = 32 * (s >> 5) + 16 * ((s >> 2) & 1) + 4 * ((s >> 3) & 3) + (s & 3);
      dstw[k * 128 + (s ^ ((k & 7) << 3))] = f2bf(Wsrc[k * stride + d]);
    }
  }
  __syncthreads();

  const int b0 = blockIdx.x * 8;
  const int k = tid & 127, bh = tid >> 7;
  for (int p = 0; p < 4; ++p) {
    const int b = b0 + p * 2;
    qrs[tid] = query_r[(size_t)(b + bh) * DIMD + k];
    __syncthreads();
    float acc = b1[k];
    const float* qq = &qrs[bh * 128];
    const float* wr = &w1b[k * 132];
    #pragma unroll
    for (int d = 0; d < 128; d += 4) {
      float4 wv = *reinterpret_cast<const float4*>(wr + d);
      float4 qv = *reinterpret_cast<const float4*>(qq + d);
      acc = fmaf(wv.x, qv.x, acc); acc = fmaf(wv.y, qv.y, acc);
      acc = fmaf(wv.z, qv.z, acc); acc = fmaf(wv.w, qv.w, acc);
    }
    qproj[(size_t)(b + bh) * DIMD + k] = acc;
    __syncthreads();
  }
}

// ---------------------------------------------------------------------------
// Main kernel: R16's verified operand-swap design (zero LDS round trips,
// pi-permuted weight tables; absmax 0.5) with REGISTER DISCIPLINE fixing
// R16's 198 MB spill (peak liveness was ~160 > the 128 cap):
//  (1) rr/ev/sv loads moved INTO the ck-quarter loop: 6 float4 transient,
//      consumed immediately into af-pack + bias-pack (no rrpk[16] array).
//  (2) GEMM2 in four 2-nt output groups: Ca = 8 regs, bias-dot folded in
//      immediately (no Ca[32]).
//  (3) sched_barrier(0) per ck and per iteration bounds load hoisting
//      (the R13/R16 spill trigger); emits no waitcnt (R15: costless).
// Peak liveness: GEMM1 ~116 (acc32+Ch32+bp16+loads24+af4), GEMM2 ~80.
// Loop: 24 global float4 + 64 LDS b128 weight reads + 64 MFMA per iter;
// NO LDS writes, NO u16 DS ops, NO fences, NO barriers after weight stage.
// LDS = 64 KB (weights only). Bare __launch_bounds__(512).
// ---------------------------------------------------------------------------
__global__ __launch_bounds__(512) void main_kernel(
    const float* __restrict__ query_emb,
    const float* __restrict__ refer_embs, const float* __restrict__ refer_r,
    const float* __restrict__ start_embs, const float* __restrict__ b2,
    const float* __restrict__ qproj, const unsigned short* __restrict__ w1a_t,
    const unsigned short* __restrict__ w2_t, float* __restrict__ out)
{
  __shared__ unsigned short lds_w1a[128 * 128];   // 32 KB, permuted+swizzled
  __shared__ unsigned short lds_w2[128 * 128];    // 32 KB, permuted+swizzled

  const int tid  = threadIdx.x;
  const int wave = tid >> 6;
  const int lane = tid & 63;
  const int g    = lane >> 4;   // 0..3
  const int c    = lane & 15;   // r-lane / weight-row-lane

  { // stage weight tables (linear uint4 copy; layout pre-applied in ws)
    const uint4* s1 = reinterpret_cast<const uint4*>(w1a_t);
    const uint4* s2 = reinterpret_cast<const uint4*>(w2_t);
    uint4* d1 = reinterpret_cast<uint4*>(lds_w1a);
    uint4* d2 = reinterpret_cast<uint4*>(lds_w2);
    #pragma unroll
    for (int i = 0; i < 4; ++i) {
      d1[tid + 512 * i] = s1[tid + 512 * i];
      d2[tid + 512 * i] = s2[tid + 512 * i];
    }
  }
  __syncthreads();   // the ONLY barrier

  const int swc = (c & 7) << 3;
  const int b = blockIdx.x * 8 + wave;  // this wave's b

  f32x4 acc[8];
  #pragma unroll
  for (int nt = 0; nt < 8; ++nt) acc[nt] = (f32x4){0.f, 0.f, 0.f, 0.f};

  union U16x8 { unsigned int u[4]; s16x8 v; };

  for (int it = 0; it < 4; ++it) {
    const size_t rowoff = ((size_t)b * RR + it * 16 + c) * DIMD + 4 * g;
    const float* rp = refer_r    + rowoff;
    const float* ep = refer_embs + rowoff;
    const float* sp = start_embs + rowoff;

    unsigned int bp[16];

    // ---- GEMM1: Ch[k=16nt+4g+reg, r=c] = W1a x rr + qproj
    f32x4 Ch[8];
    #pragma unroll
    for (int nt = 0; nt < 8; ++nt)
      Ch[nt] = *reinterpret_cast<const f32x4*>(qproj + (size_t)b * DIMD + 16 * nt + 4 * g);

    #pragma unroll
    for (int ck = 0; ck < 4; ++ck) {
      // per-quarter loads (transient: 6 float4 = 24 VGPR, die this ck)
      const float4 rv0 = *reinterpret_cast<const float4*>(rp + 32 * ck);
      const float4 rv1 = *reinterpret_cast<const float4*>(rp + 32 * ck + 16);
      const float4 ev0 = *reinterpret_cast<const float4*>(ep + 32 * ck);
      const float4 ev1 = *reinterpret_cast<const float4*>(ep + 32 * ck + 16);
      const float4 sv0 = *reinterpret_cast<const float4*>(sp + 32 * ck);
      const float4 sv1 = *reinterpret_cast<const float4*>(sp + 32 * ck + 16);
      U16x8 af;
      af.u[0] = pk2(rv0.x, rv0.y); af.u[1] = pk2(rv0.z, rv0.w);
      af.u[2] = pk2(rv1.x, rv1.y); af.u[3] = pk2(rv1.z, rv1.w);
      bp[4 * ck + 0] = pk2(ev0.x - sv0.x - rv0.x, ev0.y - sv0.y - rv0.y);
      bp[4 * ck + 1] = pk2(ev0.z - sv0.z - rv0.z, ev0.w - sv0.w - rv0.w);
      bp[4 * ck + 2] = pk2(ev1.x - sv1.x - rv1.x, ev1.y - sv1.y - rv1.y);
      bp[4 * ck + 3] = pk2(ev1.z - sv1.z - rv1.z, ev1.w - sv1.w - rv1.w);
      #pragma unroll
      for (int nt = 0; nt < 8; ++nt) {
        s16x8 wf = *reinterpret_cast<const s16x8*>(
            &lds_w1a[(nt * 16 + c) * DIMD + ((ck * 32 + g * 8) ^ swc)]);
        Ch[nt] = __builtin_amdgcn_mfma_f32_16x16x32_bf16(wf, af.v, Ch[nt], 0, 0, 0);
      }
      __builtin_amdgcn_sched_barrier(0);   // bound hoisting to one quarter
    }

    // ---- relu + pack h (in-lane; layout already matches GEMM2 B-frag)
    unsigned int hpk[16];
    #pragma unroll
    for (int nt = 0; nt < 8; ++nt) {
      hpk[2 * nt + 0] = pk2(fmaxf(Ch[nt][0], 0.f), fmaxf(Ch[nt][1], 0.f));
      hpk[2 * nt + 1] = pk2(fmaxf(Ch[nt][2], 0.f), fmaxf(Ch[nt][3], 0.f));
    }

    // ---- GEMM2 in 2-nt output groups (Ca = 8 regs, dot folded in)
    #pragma unroll
    for (int ntg = 0; ntg < 4; ++ntg) {
      f32x4 Ca0 = *reinterpret_cast<const f32x4*>(b2 + 32 * ntg + 4 * g);
      f32x4 Ca1 = *reinterpret_cast<const f32x4*>(b2 + 32 * ntg + 16 + 4 * g);
      #pragma unroll
      for (int ck = 0; ck < 4; ++ck) {
        U16x8 hf;
        hf.u[0] = hpk[4 * ck + 0]; hf.u[1] = hpk[4 * ck + 1];
        hf.u[2] = hpk[4 * ck + 2]; hf.u[3] = hpk[4 * ck + 3];
        s16x8 w0 = *reinterpret_cast<const s16x8*>(
            &lds_w2[((2 * ntg) * 16 + c) * DIMD + ((ck * 32 + g * 8) ^ swc)]);
        s16x8 w1 = *reinterpret_cast<const s16x8*>(
            &lds_w2[((2 * ntg + 1) * 16 + c) * DIMD + ((ck * 32 + g * 8) ^ swc)]);
        Ca0 = __builtin_amdgcn_mfma_f32_16x16x32_bf16(w0, hf.v, Ca0, 0, 0, 0);
        Ca1 = __builtin_amdgcn_mfma_f32_16x16x32_bf16(w1, hf.v, Ca1, 0, 0, 0);
      }
      acc[2 * ntg][0]     = fmaf(Ca0[0], bflo(bp[4 * ntg + 0]), acc[2 * ntg][0]);
      acc[2 * ntg][1]     = fmaf(Ca0[1], bfhi(bp[4 * ntg + 0]), acc[2 * ntg][1]);
      acc[2 * ntg][2]     = fmaf(Ca0[2], bflo(bp[4 * ntg + 1]), acc[2 * ntg][2]);
      acc[2 * ntg][3]     = fmaf(Ca0[3], bfhi(bp[4 * ntg + 1]), acc[2 * ntg][3]);
      acc[2 * ntg + 1][0] = fmaf(Ca1[0], bflo(bp[4 * ntg + 2]), acc[2 * ntg + 1][0]);
      acc[2 * ntg + 1][1] = fmaf(Ca1[1], bfhi(bp[4 * ntg + 2]), acc[2 * ntg + 1][1]);
      acc[2 * ntg + 1][2] = fmaf(Ca1[2], bflo(bp[4 * ntg + 3]), acc[2 * ntg + 1][2]);
      acc[2 * ntg + 1][3] = fmaf(Ca1[3], bfhi(bp[4 * ntg + 3]), acc[2 * ntg + 1][3]);
    }
    __builtin_amdgcn_sched_barrier(0);   // keep iterations from merging
  }

  // ---- r-sum butterfly over the 16 c-lanes (once per b)
  #pragma unroll
  for (int mask = 1; mask <= 8; mask <<= 1)
    #pragma unroll
    for (int nt = 0; nt < 8; ++nt) {
      acc[nt][0] += __shfl_xor(acc[nt][0], mask);
      acc[nt][1] += __shfl_xor(acc[nt][1], mask);
      acc[nt][2] += __shfl_xor(acc[nt][2], mask);
      acc[nt][3] += __shfl_xor(acc[nt][3], mask);
    }

  // ---- epilogue: lanes c==0 (4 lanes, g=0..3) write d=16nt+4g..+3
  if (c == 0) {
    #pragma unroll
    for (int nt = 0; nt < 8; ++nt) {
      const size_t o = (size_t)b * DIMD + 16 * nt + 4 * g;
      const float4 qe = *reinterpret_cast<const float4*>(query_emb + o);
      float4 r;
      r.x = qe.x + acc[nt][0]; r.y = qe.y + acc[nt][1];
      r.z = qe.z + acc[nt][2]; r.w = qe.w + acc[nt][3];
      *reinterpret_cast<float4*>(out + o) = r;
    }
  }
}

extern "C" void kernel_launch(void* const* d_in, const int* in_sizes, int n_in,
                              void* d_out, int out_size, void* d_ws, size_t ws_size,
                              hipStream_t stream) {
  const float* query_emb  = (const float*)d_in[0];
  const float* offset_emb = (const float*)d_in[1];
  const float* refer_embs = (const float*)d_in[2];
  const float* query_r    = (const float*)d_in[3];
  const float* refer_r    = (const float*)d_in[4];
  const float* start_embs = (const float*)d_in[5];
  const float* W1 = (const float*)d_in[6];
  const float* b1 = (const float*)d_in[7];
  const float* W2 = (const float*)d_in[8];
  const float* b2 = (const float*)d_in[9];
  float* out = (float*)d_out;

  float* qproj = (float*)d_ws;                       // 4096*128 f32 = 2 MB
  unsigned short* w1a_t =
      (unsigned short*)((char*)d_ws + (size_t)BTOT * DIMD * sizeof(float));
  unsigned short* w2_t = w1a_t + 128 * 128;          // +32 KB each

  hipLaunchKernelGGL(prep_kernel, dim3(512), dim3(256), 0, stream,
                     W1, b1, query_r, W2, offset_emb, qproj, w1a_t, w2_t, out);
  hipLaunchKernelGGL(main_kernel, dim3(512), dim3(512), 0, stream,
                     query_emb, refer_embs, refer_r, start_embs,
                     b2, qproj, w1a_t, w2_t, out);
}